// Round 3
// baseline (3185.216 us; speedup 1.0000x reference)
//
#include <hip/hip_runtime.h>
#include <hip/hip_bf16.h>

// Problem constants
#define NB   64     // batch
#define NDEC 12     // decoder steps
#define NF   32     // input features
#define NH   512    // hidden
#define NE   96     // encoder length
#define NT   4      // output dim

// bf16 helpers (used only for the enc_proj workspace cache)
__device__ __forceinline__ float bf2f(unsigned short u) {
    return __uint_as_float(((unsigned int)u) << 16);
}
__device__ __forceinline__ unsigned short f2bf(float f) {
    unsigned int u = __float_as_uint(f);
    unsigned int r = (u + 0x7fffu + ((u >> 16) & 1u)) >> 16;   // RNE
    return (unsigned short)r;
}

struct f8 { float v[8]; };
__device__ __forceinline__ f8 load8f(const float* p) {   // 32B, needs 16B align
    float4 a = *(const float4*)p;
    float4 b = *(const float4*)(p + 4);
    f8 r;
    r.v[0]=a.x; r.v[1]=a.y; r.v[2]=a.z; r.v[3]=a.w;
    r.v[4]=b.x; r.v[5]=b.y; r.v[6]=b.z; r.v[7]=b.w;
    return r;
}

// ---------------------------------------------------------------------------
// Init: h0/h1 (parity-0 buffers) and cur(0) = inputs[:,0,:], fp32 [dim][batch]
__global__ __launch_bounds__(256) void k_init(const float* __restrict__ hidden,
                                              const float* __restrict__ inputs,
                                              float* __restrict__ h0, float* __restrict__ h1,
                                              float* __restrict__ cur) {
    int b = blockIdx.x, tid = threadIdx.x;
    for (int k = tid; k < NH; k += 256) {
        h0[k*NB + b] = hidden[b*NH + k];
        h1[k*NB + b] = hidden[NB*NH + b*NH + k];
    }
    if (tid < NF) cur[tid*NB + b] = inputs[b*NDEC*NF + tid];
}

// ---------------------------------------------------------------------------
// enc_proj[be][g] = sum_h enc[be][h] * W_attn[g][512+h]; stored as bf16
__global__ __launch_bounds__(256) void k_encproj(const float* __restrict__ enc,
                                                 const float* __restrict__ Wattn,
                                                 unsigned short* __restrict__ encp) {
    __shared__ float As[64][17];
    __shared__ float Bs[64][17];
    int bx = blockIdx.x & 7;    // g tile
    int by = blockIdx.x >> 3;   // be tile
    int tid = threadIdx.x;
    int tx = tid & 15, ty = tid >> 4;
    int arow = tid >> 2;            // 0..63
    int akk  = (tid & 3) * 4;       // 0,4,8,12
    const float* Abase = enc   + (size_t)(by*64 + arow)*NH;
    const float* Bbase = Wattn + (size_t)(bx*64 + arow)*(2*NH) + NH;
    float acc[4][4] = {};
    for (int k0 = 0; k0 < NH; k0 += 16) {
        float4 av = *(const float4*)(Abase + k0 + akk);
        float4 bv = *(const float4*)(Bbase + k0 + akk);
        As[arow][akk+0] = av.x; As[arow][akk+1] = av.y;
        As[arow][akk+2] = av.z; As[arow][akk+3] = av.w;
        Bs[arow][akk+0] = bv.x; Bs[arow][akk+1] = bv.y;
        Bs[arow][akk+2] = bv.z; Bs[arow][akk+3] = bv.w;
        __syncthreads();
        #pragma unroll 4
        for (int k = 0; k < 16; ++k) {
            float a0 = As[ty*4+0][k], a1 = As[ty*4+1][k], a2 = As[ty*4+2][k], a3 = As[ty*4+3][k];
            float b0 = Bs[tx*4+0][k], b1 = Bs[tx*4+1][k], b2 = Bs[tx*4+2][k], b3 = Bs[tx*4+3][k];
            acc[0][0] += a0*b0; acc[0][1] += a0*b1; acc[0][2] += a0*b2; acc[0][3] += a0*b3;
            acc[1][0] += a1*b0; acc[1][1] += a1*b1; acc[1][2] += a1*b2; acc[1][3] += a1*b3;
            acc[2][0] += a2*b0; acc[2][1] += a2*b1; acc[2][2] += a2*b2; acc[2][3] += a2*b3;
            acc[3][0] += a3*b0; acc[3][1] += a3*b1; acc[3][2] += a3*b2; acc[3][3] += a3*b3;
        }
        __syncthreads();
    }
    #pragma unroll
    for (int i = 0; i < 4; ++i)
        #pragma unroll
        for (int j = 0; j < 4; ++j)
            encp[(size_t)(by*64 + ty*4 + i)*NH + bx*64 + tx*4 + j] = f2bf(acc[i][j]);
}

// ---------------------------------------------------------------------------
// Per-step: out(s-1) projection + cur(s) scatter-update + attention -> ws(s).
// One block per batch element. do_attn=0 for the final out-only pass.
__global__ __launch_bounds__(256) void k_attn(
    const unsigned short* __restrict__ encp,   // bf16 [6144][512]
    const float* __restrict__ enc,
    const float* __restrict__ Wattn,
    const float* __restrict__ battn,
    const float* __restrict__ vattn,
    const float* __restrict__ Wout,
    const float* __restrict__ bout,
    const float* __restrict__ inputs,
    const int* __restrict__ tgt,
    const float* __restrict__ h1,     // h1(s), parity-resolved by host
    float* __restrict__ wsv,          // [512][64]
    float* __restrict__ cur,          // [32][64]
    float* __restrict__ out,
    int s, int do_attn)
{
    int b = blockIdx.x, tid = threadIdx.x;
    int lane = tid & 63, w = tid >> 6;
    __shared__ float h1s[NH];
    __shared__ float att[NH];
    __shared__ float vv[NH];
    __shared__ float sc[NE];
    __shared__ float outv[NT];
    __shared__ float red[2];

    for (int g = tid; g < NH; g += 256) {
        h1s[g] = h1[g*NB + b];
        vv[g]  = vattn[g];
    }
    __syncthreads();

    if (s > 0) {
        // out(s-1)[b][w] = [h1(s) | ws(s-1) | cur(s-1)] . W_out[w] + b_out[w]
        float o = 0.f;
        const float* wr = Wout + w*(2*NH + NF);
        for (int c = lane; c < 2*NH + NF; c += 64) {
            float x;
            if (c < NH)            x = h1s[c];
            else if (c < 2*NH)     x = wsv[(c-NH)*NB + b];
            else                   x = cur[(c-2*NH)*NB + b];
            o += wr[c] * x;
        }
        #pragma unroll
        for (int off = 32; off > 0; off >>= 1) o += __shfl_down(o, off);
        if (lane == 0) {
            o += bout[w];
            outv[w] = o;
            out[b*(NDEC*NT) + (s-1)*NT + w] = o;
        }
    }
    __syncthreads();

    if (do_attn) {
        if (s > 0) {
            // cur(s) = inputs[:, s-1, :] with out(s-1) scattered at target_indices
            if (tid < NF) cur[tid*NB + b] = inputs[b*NDEC*NF + (s-1)*NF + tid];
            __syncthreads();
            if (tid < NT) cur[tgt[tid]*NB + b] = outv[tid];
            __syncthreads();
        }
        // attn_h[g] = h1 . Wa_h[g] + b_attn[g]
        for (int g = tid; g < NH; g += 256) {
            const float* wrow = Wattn + (size_t)g*(2*NH);
            float a = battn[g];
            for (int h = 0; h < NH; h += 8) {
                f8 wv = load8f(wrow + h);
                #pragma unroll
                for (int i = 0; i < 8; ++i) a += wv.v[i]*h1s[h+i];
            }
            att[g] = a;
        }
        __syncthreads();
        // scores[e] = sum_g tanh(enc_proj[b,e,g] + att[g]) * v[g]
        for (int e = w; e < NE; e += 4) {
            const unsigned short* ep = encp + (size_t)(b*NE + e)*NH;
            float ssum = 0.f;
            #pragma unroll
            for (int i = 0; i < 8; ++i) {
                int g = lane + i*64;
                ssum += tanhf(bf2f(ep[g]) + att[g]) * vv[g];
            }
            #pragma unroll
            for (int off = 32; off > 0; off >>= 1) ssum += __shfl_down(ssum, off);
            if (lane == 0) sc[e] = ssum;
        }
        __syncthreads();
        if (tid == 0) {
            float m = sc[0];
            for (int e = 1; e < NE; ++e) m = fmaxf(m, sc[e]);
            red[0] = m;
        }
        __syncthreads();
        if (tid < NE) sc[tid] = expf(sc[tid] - red[0]);
        __syncthreads();
        if (tid == 0) {
            float ssum = 0.f;
            for (int e = 0; e < NE; ++e) ssum += sc[e];
            red[1] = 1.f / ssum;
        }
        __syncthreads();
        float inv = red[1];
        // ws[h] = sum_e p[e] * enc[b,e,h]
        for (int h = tid; h < NH; h += 256) {
            const float* eb = enc + (size_t)b*NE*NH + h;
            float v = 0.f;
            for (int e = 0; e < NE; ++e) v += sc[e] * eb[e*NH];
            wsv[h*NB + b] = v * inv;
        }
    }
}

// ---------------------------------------------------------------------------
// GRU cell: thread = (b, j). gi over x=[xA|xB], gh over hold, gates, write hnew.
__global__ __launch_bounds__(256) void k_gru(
    const float* __restrict__ Wi,   // (1536, KA+KB)
    const float* __restrict__ Wh,   // (1536, 512)
    const float* __restrict__ bi,
    const float* __restrict__ bh,
    const float* __restrict__ xA, int KA,    // [KA][64]
    const float* __restrict__ xB, int KB,    // [KB][64] (KB may be 0)
    const float* __restrict__ hold,          // [512][64]
    float* __restrict__ hnew)                // [512][64]
{
    int tid = threadIdx.x;
    int b = tid & 63, jl = tid >> 6;
    int j = blockIdx.x * 4 + jl;
    int KI = KA + KB;
    const float* w0 = Wi + (size_t)j*KI;
    const float* w1 = Wi + (size_t)(NH + j)*KI;
    const float* w2 = Wi + (size_t)(2*NH + j)*KI;
    float a0 = bi[j], a1 = bi[NH + j], a2 = bi[2*NH + j];
    for (int k = 0; k < KA; k += 8) {
        f8 p0 = load8f(w0 + k), p1 = load8f(w1 + k), p2 = load8f(w2 + k);
        #pragma unroll
        for (int i = 0; i < 8; ++i) {
            float x = xA[(k+i)*NB + b];
            a0 += p0.v[i]*x; a1 += p1.v[i]*x; a2 += p2.v[i]*x;
        }
    }
    for (int k = 0; k < KB; k += 8) {
        f8 p0 = load8f(w0 + KA + k), p1 = load8f(w1 + KA + k), p2 = load8f(w2 + KA + k);
        #pragma unroll
        for (int i = 0; i < 8; ++i) {
            float x = xB[(k+i)*NB + b];
            a0 += p0.v[i]*x; a1 += p1.v[i]*x; a2 += p2.v[i]*x;
        }
    }
    const float* v0 = Wh + (size_t)j*NH;
    const float* v1 = Wh + (size_t)(NH + j)*NH;
    const float* v2 = Wh + (size_t)(2*NH + j)*NH;
    float g0 = bh[j], g1 = bh[NH + j], g2 = bh[2*NH + j];
    for (int k = 0; k < NH; k += 8) {
        f8 p0 = load8f(v0 + k), p1 = load8f(v1 + k), p2 = load8f(v2 + k);
        #pragma unroll
        for (int i = 0; i < 8; ++i) {
            float hv = hold[(k+i)*NB + b];
            g0 += p0.v[i]*hv; g1 += p1.v[i]*hv; g2 += p2.v[i]*hv;
        }
    }
    float r = 1.f/(1.f + expf(-(a0 + g0)));
    float z = 1.f/(1.f + expf(-(a1 + g1)));
    float n = tanhf(a2 + r*g2);
    float hp = hold[j*NB + b];
    hnew[j*NB + b] = (1.f - z)*n + z*hp;
}

// ---------------------------------------------------------------------------
extern "C" void kernel_launch(void* const* d_in, const int* in_sizes, int n_in,
                              void* d_out, int out_size, void* d_ws, size_t ws_size,
                              hipStream_t stream) {
    const float* inputs = (const float*)d_in[0];
    const float* hidden = (const float*)d_in[1];
    const float* enc    = (const float*)d_in[2];
    const int*   tgt    = (const int*)d_in[3];
    const float* Wattn  = (const float*)d_in[4];
    const float* battn  = (const float*)d_in[5];
    const float* vattn  = (const float*)d_in[6];
    const float* Wi0    = (const float*)d_in[7];
    const float* Wh0    = (const float*)d_in[8];
    const float* bi0    = (const float*)d_in[9];
    const float* bh0    = (const float*)d_in[10];
    const float* Wi1    = (const float*)d_in[11];
    const float* Wh1    = (const float*)d_in[12];
    const float* bi1    = (const float*)d_in[13];
    const float* bh1    = (const float*)d_in[14];
    const float* Wout   = (const float*)d_in[15];
    const float* bout   = (const float*)d_in[16];
    float* out = (float*)d_out;

    // Workspace layout: small fp32 state first (663 KB), bf16 enc_proj last.
    // Total = 165,888 fp32 + 3,145,728 bf16 = ~6.96 MB.
    float* h0   = (float*)d_ws;               // 2 parities x [512][64]
    float* h1   = h0 + 2*NH*NB;               // 2 parities x [512][64]
    float* wsv  = h1 + 2*NH*NB;               // [512][64]
    float* cur  = wsv + NH*NB;                // [32][64]
    unsigned short* encp = (unsigned short*)(cur + NF*NB);   // [6144][512] bf16

    k_init<<<NB, 256, 0, stream>>>(hidden, inputs, h0, h1, cur);
    k_encproj<<<(NB*NE/64)*(NH/64), 256, 0, stream>>>(enc, Wattn, encp);

    for (int s = 0; s < NDEC; ++s) {
        int par = s & 1;
        k_attn<<<NB, 256, 0, stream>>>(encp, enc, Wattn, battn, vattn, Wout, bout,
                                       inputs, tgt, h1 + par*NH*NB, wsv, cur, out, s, 1);
        k_gru<<<NH/4, 256, 0, stream>>>(Wi0, Wh0, bi0, bh0,
                                        cur, NF, wsv, NH,
                                        h0 + par*NH*NB, h0 + (par^1)*NH*NB);
        k_gru<<<NH/4, 256, 0, stream>>>(Wi1, Wh1, bi1, bh1,
                                        h0 + (par^1)*NH*NB, NH, wsv, 0,
                                        h1 + par*NH*NB, h1 + (par^1)*NH*NB);
    }
    // Final out(11) projection only (h1(12) is in parity buffer 0)
    k_attn<<<NB, 256, 0, stream>>>(encp, enc, Wattn, battn, vattn, Wout, bout,
                                   inputs, tgt, h1 + 0*NH*NB, wsv, cur, out, NDEC, 0);
}

// Round 4
// 1255.921 us; speedup vs baseline: 2.5362x; 2.5362x over previous
//
#include <hip/hip_runtime.h>
#include <hip/hip_bf16.h>

// Problem constants
#define NB   64     // batch
#define NDEC 12     // decoder steps
#define NF   32     // input features
#define NH   512    // hidden
#define NE   96     // encoder length
#define NT   4      // output dim

__device__ __forceinline__ float bf2f(unsigned short u) {
    return __uint_as_float(((unsigned int)u) << 16);
}
__device__ __forceinline__ unsigned short f2bf(float f) {
    unsigned int u = __float_as_uint(f);
    return (unsigned short)((u + 0x7fffu + ((u >> 16) & 1u)) >> 16);   // RNE
}
// fast tanh/sigmoid via v_exp; clamp tanh arg to avoid inf/inf=NaN
__device__ __forceinline__ float fast_tanh(float x) {
    x = fminf(fmaxf(x, -15.f), 15.f);
    float e = __expf(2.f * x);
    return (e - 1.f) / (e + 1.f);
}
__device__ __forceinline__ float fast_sig(float x) {
    return 1.f / (1.f + __expf(-x));
}

// ---------------------------------------------------------------------------
// Init: h0/h1 parity-0 (col layout [512][64]) and cur(0) col [32][64]
__global__ __launch_bounds__(256) void k_init(const float* __restrict__ hidden,
                                              const float* __restrict__ inputs,
                                              float* __restrict__ h0, float* __restrict__ h1,
                                              float* __restrict__ cur) {
    int b = blockIdx.x, tid = threadIdx.x;
    for (int k = tid; k < NH; k += 256) {
        h0[k*NB + b] = hidden[b*NH + k];
        h1[k*NB + b] = hidden[NB*NH + b*NH + k];
    }
    if (tid < NF) cur[tid*NB + b] = inputs[b*NDEC*NF + tid];
}

// ---------------------------------------------------------------------------
// enc_proj[be][g] = sum_h enc[be][h] * W_attn[g][512+h]; stored bf16
__global__ __launch_bounds__(256) void k_encproj(const float* __restrict__ enc,
                                                 const float* __restrict__ Wattn,
                                                 unsigned short* __restrict__ encp) {
    __shared__ float As[64][17];
    __shared__ float Bs[64][17];
    int bx = blockIdx.x & 7;    // g tile
    int by = blockIdx.x >> 3;   // be tile
    int tid = threadIdx.x;
    int tx = tid & 15, ty = tid >> 4;
    int arow = tid >> 2;
    int akk  = (tid & 3) * 4;
    const float* Abase = enc   + (size_t)(by*64 + arow)*NH;
    const float* Bbase = Wattn + (size_t)(bx*64 + arow)*(2*NH) + NH;
    float acc[4][4] = {};
    for (int k0 = 0; k0 < NH; k0 += 16) {
        float4 av = *(const float4*)(Abase + k0 + akk);
        float4 bv = *(const float4*)(Bbase + k0 + akk);
        As[arow][akk+0] = av.x; As[arow][akk+1] = av.y;
        As[arow][akk+2] = av.z; As[arow][akk+3] = av.w;
        Bs[arow][akk+0] = bv.x; Bs[arow][akk+1] = bv.y;
        Bs[arow][akk+2] = bv.z; Bs[arow][akk+3] = bv.w;
        __syncthreads();
        #pragma unroll 4
        for (int k = 0; k < 16; ++k) {
            float a0 = As[ty*4+0][k], a1 = As[ty*4+1][k], a2 = As[ty*4+2][k], a3 = As[ty*4+3][k];
            float b0 = Bs[tx*4+0][k], b1 = Bs[tx*4+1][k], b2 = Bs[tx*4+2][k], b3 = Bs[tx*4+3][k];
            acc[0][0] += a0*b0; acc[0][1] += a0*b1; acc[0][2] += a0*b2; acc[0][3] += a0*b3;
            acc[1][0] += a1*b0; acc[1][1] += a1*b1; acc[1][2] += a1*b2; acc[1][3] += a1*b3;
            acc[2][0] += a2*b0; acc[2][1] += a2*b1; acc[2][2] += a2*b2; acc[2][3] += a2*b3;
            acc[3][0] += a3*b0; acc[3][1] += a3*b1; acc[3][2] += a3*b2; acc[3][3] += a3*b3;
        }
        __syncthreads();
    }
    #pragma unroll
    for (int i = 0; i < 4; ++i)
        #pragma unroll
        for (int j = 0; j < 4; ++j)
            encp[(size_t)(by*64 + ty*4 + i)*NH + bx*64 + tx*4 + j] = f2bf(acc[i][j]);
}

// ---------------------------------------------------------------------------
// Phase A: att[b][g] GEMM (512 blocks = 64 b x 8 g-tiles, 4-way K-split).
// gt==0 blocks also: out(s-1) projection + cur(s) scatter-update.
// do_att=0 (final pass): grid=64, out-only.
__global__ __launch_bounds__(256) void k_att(
    const float* __restrict__ Wattn, const float* __restrict__ battn,
    const float* __restrict__ h1c,    // [512][64] h1(s)
    float* __restrict__ attb,         // [64][512]
    const float* __restrict__ slab,   // [2][512][64] unnormalized ws(s-1)
    const float* __restrict__ Dp,     // [2][64]
    float* __restrict__ curc,         // [32][64]
    const float* __restrict__ Wout, const float* __restrict__ bout,
    const float* __restrict__ inputs, const int* __restrict__ tgt,
    float* __restrict__ out, int s, int do_att)
{
    int blk = blockIdx.x;
    int b  = do_att ? (blk >> 3) : blk;
    int gt = do_att ? (blk & 7) : 0;
    int t = threadIdx.x;
    __shared__ float h1s[NH];
    __shared__ float part[64][4];
    __shared__ float outsh[NT];
    h1s[t]       = h1c[t*NB + b];
    h1s[t + 256] = h1c[(t + 256)*NB + b];
    __syncthreads();

    if (do_att) {
        int gl = t >> 2, kq = t & 3;
        const float* wr = Wattn + (size_t)(gt*64 + gl)*(2*NH) + kq*128;
        const float* hh = h1s + kq*128;
        float acc = 0.f;
        #pragma unroll 8
        for (int i = 0; i < 128; i += 4) {
            float4 w4 = *(const float4*)(wr + i);
            acc += w4.x*hh[i] + w4.y*hh[i+1] + w4.z*hh[i+2] + w4.w*hh[i+3];
        }
        part[gl][kq] = acc;
    }
    __syncthreads();
    if (do_att && t < 64) {
        float a = part[t][0] + part[t][1] + part[t][2] + part[t][3] + battn[gt*64 + t];
        attb[b*NH + gt*64 + t] = a;
    }

    if (gt == 0 && s > 0) {
        int lane = t & 63, w = t >> 6;
        float invD = 1.f / (Dp[b] + Dp[64 + b]);
        const float* wr = Wout + (size_t)w*(2*NH + NF);
        float o = 0.f;
        for (int c = lane; c < 2*NH + NF; c += 64) {
            float x;
            if (c < NH)        x = h1s[c];
            else if (c < 2*NH) { int k = c - NH; x = (slab[k*NB + b] + slab[NH*NB + k*NB + b]) * invD; }
            else               x = curc[(c - 2*NH)*NB + b];
            o += wr[c] * x;
        }
        #pragma unroll
        for (int off = 32; off; off >>= 1) o += __shfl_down(o, off);
        if (lane == 0) {
            o += bout[w];
            outsh[w] = o;
            out[b*(NDEC*NT) + (s-1)*NT + w] = o;
        }
        __syncthreads();
        if (do_att) {   // continuing step: refresh cur(s)
            if (t < NF) curc[t*NB + b] = inputs[b*(NDEC*NF) + (s-1)*NF + t];
            __syncthreads();
            if (t < NT) curc[tgt[t]*NB + b] = outsh[t];
        }
    }
}

// ---------------------------------------------------------------------------
// Phase BC: scores (tanh-dot) + exp + partial denominator + unnormalized ws.
// 128 blocks = 64 b x 2 e-halves (48 e each).
__global__ __launch_bounds__(256) void k_scorews(
    const float* __restrict__ attb, const unsigned short* __restrict__ encp,
    const float* __restrict__ vattn, const float* __restrict__ enc,
    float* __restrict__ slab, float* __restrict__ Dp)
{
    int b = blockIdx.x >> 1, half = blockIdx.x & 1;
    int t = threadIdx.x, lane = t & 63, w = t >> 6;
    __shared__ float atts[NH];
    __shared__ float vs[NH];
    __shared__ float pe[48];
    atts[t]     = attb[b*NH + t];
    atts[t+256] = attb[b*NH + t + 256];
    vs[t]       = vattn[t];
    vs[t+256]   = vattn[t + 256];
    __syncthreads();
    for (int el = w; el < 48; el += 4) {
        int e = half*48 + el;
        const unsigned short* ep = encp + (size_t)(b*NE + e)*NH;
        float s = 0.f;
        #pragma unroll
        for (int i = 0; i < 8; ++i) {
            int g = lane + i*64;
            s += fast_tanh(bf2f(ep[g]) + atts[g]) * vs[g];
        }
        #pragma unroll
        for (int off = 32; off; off >>= 1) s += __shfl_down(s, off);
        if (lane == 0) pe[el] = __expf(s);   // no max-subtract: |s| small, safe
    }
    __syncthreads();
    if (t == 0) {
        float d = 0.f;
        for (int i = 0; i < 48; ++i) d += pe[i];
        Dp[half*64 + b] = d;
    }
    float* sl = slab + half*NH*NB;
    for (int h = t; h < NH; h += 256) {
        const float* eb = enc + (size_t)(b*NE + half*48)*NH + h;
        float acc = 0.f;
        #pragma unroll 4
        for (int el = 0; el < 48; ++el) acc += pe[el] * eb[el*NH];
        sl[h*NB + b] = acc;
    }
}

// ---------------------------------------------------------------------------
// GRU: 512 blocks (block = one j), thread = (b, K-quarter), LDS combine.
// Virtual x = [xA (KA) | slab*invD (KS)] for Wi; hold (512) for Wh.
__global__ __launch_bounds__(256) void k_gru(
    const float* __restrict__ Wi, const float* __restrict__ Wh,
    const float* __restrict__ bi, const float* __restrict__ bh,
    const float* __restrict__ xA, int KA,
    const float* __restrict__ slab, int KS,
    const float* __restrict__ Dp,
    const float* __restrict__ hold, float* __restrict__ hnew)
{
    int j = blockIdx.x;
    int t = threadIdx.x, b = t & 63, kq = t >> 6;
    int KI = KA + KS;
    int K4 = (KI + NH) >> 2;
    int k0 = kq*K4, k1 = k0 + K4;
    const float* w0 = Wi + (size_t)j*KI;
    const float* w1 = Wi + (size_t)(NH + j)*KI;
    const float* w2 = Wi + (size_t)(2*NH + j)*KI;
    float invD = (KS > 0) ? 1.f / (Dp[b] + Dp[64 + b]) : 0.f;
    float s0 = 0.f, s1 = 0.f, a2 = 0.f, g2 = 0.f;
    int aE = min(k1, KA);
    #pragma unroll 4
    for (int k = k0; k < aE; ++k) {
        float x = xA[k*NB + b];
        s0 += w0[k]*x; s1 += w1[k]*x; a2 += w2[k]*x;
    }
    int sB = max(k0, KA), sE = min(k1, KI);
    #pragma unroll 4
    for (int k = sB; k < sE; ++k) {
        int kx = k - KA;
        float x = (slab[kx*NB + b] + slab[NH*NB + kx*NB + b]) * invD;
        s0 += w0[k]*x; s1 += w1[k]*x; a2 += w2[k]*x;
    }
    const float* v0 = Wh + (size_t)j*NH;
    const float* v1 = Wh + (size_t)(NH + j)*NH;
    const float* v2 = Wh + (size_t)(2*NH + j)*NH;
    int hB = max(k0, KI);
    #pragma unroll 4
    for (int k = hB; k < k1; ++k) {
        int kh = k - KI;
        float hv = hold[kh*NB + b];
        s0 += v0[kh]*hv; s1 += v1[kh]*hv; g2 += v2[kh]*hv;
    }
    __shared__ float red[4][64][4];
    red[kq][b][0] = s0; red[kq][b][1] = s1; red[kq][b][2] = a2; red[kq][b][3] = g2;
    __syncthreads();
    if (t < 64) {
        float S0 = 0.f, S1 = 0.f, A2 = 0.f, G2 = 0.f;
        #pragma unroll
        for (int q = 0; q < 4; ++q) {
            S0 += red[q][t][0]; S1 += red[q][t][1];
            A2 += red[q][t][2]; G2 += red[q][t][3];
        }
        float r = fast_sig(S0 + bi[j] + bh[j]);
        float z = fast_sig(S1 + bi[NH + j] + bh[NH + j]);
        float n = fast_tanh(A2 + bi[2*NH + j] + r*(G2 + bh[2*NH + j]));
        float hp = hold[j*NB + t];
        hnew[j*NB + t] = (1.f - z)*n + z*hp;
    }
}

// ---------------------------------------------------------------------------
extern "C" void kernel_launch(void* const* d_in, const int* in_sizes, int n_in,
                              void* d_out, int out_size, void* d_ws, size_t ws_size,
                              hipStream_t stream) {
    const float* inputs = (const float*)d_in[0];
    const float* hidden = (const float*)d_in[1];
    const float* enc    = (const float*)d_in[2];
    const int*   tgt    = (const int*)d_in[3];
    const float* Wattn  = (const float*)d_in[4];
    const float* battn  = (const float*)d_in[5];
    const float* vattn  = (const float*)d_in[6];
    const float* Wi0    = (const float*)d_in[7];
    const float* Wh0    = (const float*)d_in[8];
    const float* bi0    = (const float*)d_in[9];
    const float* bh0    = (const float*)d_in[10];
    const float* Wi1    = (const float*)d_in[11];
    const float* Wh1    = (const float*)d_in[12];
    const float* bi1    = (const float*)d_in[13];
    const float* bh1    = (const float*)d_in[14];
    const float* Wout   = (const float*)d_in[15];
    const float* bout   = (const float*)d_in[16];
    float* out = (float*)d_out;

    // Workspace: fp32 state (~0.9 MB) + bf16 enc_proj (6.29 MB) ≈ 7.2 MB
    float* h0c  = (float*)d_ws;              // 2 x [512][64]
    float* h1c  = h0c + 2*NH*NB;             // 2 x [512][64]
    float* attb = h1c + 2*NH*NB;             // [64][512]
    float* slab = attb + NH*NB;              // 2 x [512][64] unnormalized ws
    float* Dp   = slab + 2*NH*NB;            // [2][64]
    float* curc = Dp + 128;                  // [32][64]
    unsigned short* encp = (unsigned short*)(curc + NF*NB);  // [6144][512] bf16

    k_init<<<NB, 256, 0, stream>>>(hidden, inputs, h0c, h1c, curc);
    k_encproj<<<768, 256, 0, stream>>>(enc, Wattn, encp);

    for (int s = 0; s < NDEC; ++s) {
        int par = s & 1;
        k_att<<<512, 256, 0, stream>>>(Wattn, battn, h1c + par*NH*NB, attb, slab, Dp,
                                       curc, Wout, bout, inputs, tgt, out, s, 1);
        k_scorews<<<128, 256, 0, stream>>>(attb, encp, vattn, enc, slab, Dp);
        k_gru<<<512, 256, 0, stream>>>(Wi0, Wh0, bi0, bh0,
                                       curc, NF, slab, NH, Dp,
                                       h0c + par*NH*NB, h0c + (par^1)*NH*NB);
        k_gru<<<512, 256, 0, stream>>>(Wi1, Wh1, bi1, bh1,
                                       h0c + (par^1)*NH*NB, NH, nullptr, 0, Dp,
                                       h1c + par*NH*NB, h1c + (par^1)*NH*NB);
    }
    // Final out(11) projection only; h1(12) is in parity buffer 0
    k_att<<<NB, 256, 0, stream>>>(Wattn, battn, h1c, attb, slab, Dp,
                                  curc, Wout, bout, inputs, tgt, out, NDEC, 0);
}